// Round 1
// baseline (1801.030 us; speedup 1.0000x reference)
//
#include <hip/hip_runtime.h>
#include <math.h>

#define NUM_USER 150000
#define NUM_ITEM 75000
#define N_TOTAL  225000
#define D        64
#define LAYERS   3
#define SCALE    0.01f

// ---------------------------------------------------------------------------
// init: A = concat(user_emb, item_emb); B = 0; acc = 0    (float4 vectorized)
// ---------------------------------------------------------------------------
__global__ void k_init(const float4* __restrict__ ue, const float4* __restrict__ ie,
                       float4* __restrict__ A, float4* __restrict__ B,
                       float4* __restrict__ acc, int n4, int nu4) {
    const float4 z = make_float4(0.f, 0.f, 0.f, 0.f);
    for (int i = blockIdx.x * blockDim.x + threadIdx.x; i < n4;
         i += gridDim.x * blockDim.x) {
        A[i]   = (i < nu4) ? ue[i] : ie[i - nu4];
        B[i]   = z;
        acc[i] = z;
    }
}

// ---------------------------------------------------------------------------
// spmm: y[r,:] += val * x[c,:]  via one wave per edge, lane = dim.
// Gather x[c*64+lane] and atomicAdd y[r*64+lane] are both coalesced 256B.
// ---------------------------------------------------------------------------
__global__ void k_spmm(const int* __restrict__ rows, const int* __restrict__ cols,
                       const float* __restrict__ vals, const float* __restrict__ x,
                       float* __restrict__ y, int nnz) {
    const int lane  = threadIdx.x & 63;
    const int wave0 = (blockIdx.x * blockDim.x + threadIdx.x) >> 6;
    const int nw    = (gridDim.x * blockDim.x) >> 6;
    for (int e = wave0; e < nnz; e += nw) {
        // edge index is wave-uniform; force scalar loads of metadata
        int   eu = __builtin_amdgcn_readfirstlane(e);
        int   r  = rows[eu];
        int   c  = cols[eu];
        float v  = vals[eu];
        float xv = x[(size_t)c * D + lane];
        atomicAdd(&y[(size_t)r * D + lane], v * xv);
    }
}

// ---------------------------------------------------------------------------
// post-layer: acc += B; zero A (A becomes next layer's output buffer)
// ---------------------------------------------------------------------------
__global__ void k_post(float4* __restrict__ acc, const float4* __restrict__ bsrc,
                       float4* __restrict__ azero, int n4) {
    const float4 z = make_float4(0.f, 0.f, 0.f, 0.f);
    for (int i = blockIdx.x * blockDim.x + threadIdx.x; i < n4;
         i += gridDim.x * blockDim.x) {
        float4 av = acc[i];
        float4 bv = bsrc[i];
        av.x += bv.x; av.y += bv.y; av.z += bv.z; av.w += bv.w;
        acc[i]   = av;
        azero[i] = z;
    }
}

// ---------------------------------------------------------------------------
// final: mean = acc/3; logstd = mean @ W + b; std = exp(logstd);
//        view1/2 = mean + std*noise*SCALE
// One wave per row; W staged in LDS (W[k*64+lane]: bank = lane%32, 2-way free).
// ---------------------------------------------------------------------------
__global__ __launch_bounds__(256) void k_final(
        float* __restrict__ mean_io,           // acc in, mean out (in place)
        const float* __restrict__ W, const float* __restrict__ bias,
        const float* __restrict__ n1, const float* __restrict__ n2,
        float* __restrict__ std_out, float* __restrict__ v1,
        float* __restrict__ v2, int nrows) {
    __shared__ float Wl[64 * 64];
    __shared__ float rowbuf[4][64];
    for (int i = threadIdx.x; i < 64 * 64; i += blockDim.x) Wl[i] = W[i];
    __syncthreads();

    const int   lane = threadIdx.x & 63;
    const int   wv   = threadIdx.x >> 6;
    const float bj   = bias[lane];
    const int   w0   = blockIdx.x * 4 + wv;
    const int   nw   = gridDim.x * 4;

    for (int r = w0; r < nrows; r += nw) {
        const size_t base = (size_t)r * D;
        float m = mean_io[base + lane] * (1.f / 3.f);
        rowbuf[wv][lane] = m;               // intra-wave: no barrier needed
        float s = bj;
#pragma unroll
        for (int k = 0; k < 64; ++k)
            s = fmaf(rowbuf[wv][k], Wl[k * 64 + lane], s);
        float sd = __expf(s);
        mean_io[base + lane] = m;
        std_out[base + lane] = sd;
        v1[base + lane] = fmaf(sd * SCALE, n1[base + lane], m);
        v2[base + lane] = fmaf(sd * SCALE, n2[base + lane], m);
    }
}

// ---------------------------------------------------------------------------
extern "C" void kernel_launch(void* const* d_in, const int* in_sizes, int n_in,
                              void* d_out, int out_size, void* d_ws, size_t ws_size,
                              hipStream_t stream) {
    const float* ue   = (const float*)d_in[0];
    const float* ie   = (const float*)d_in[1];
    const float* W    = (const float*)d_in[2];
    const float* bias = (const float*)d_in[3];
    const int*   rows = (const int*)d_in[4];
    const int*   cols = (const int*)d_in[5];
    const float* vals = (const float*)d_in[6];
    const float* n1   = (const float*)d_in[7];
    const float* n2   = (const float*)d_in[8];
    const int    nnz  = in_sizes[4];

    float* out = (float*)d_out;
    const size_t ND = (size_t)N_TOTAL * D;

    // d_out layout: [mean | std | view1 | view2].  Use view segments as
    // ego ping-pong scratch and the mean segment as the accumulator; the
    // final kernel rewrites all four segments.
    float* acc  = out;            // mean segment
    float* stdo = out + ND;       // std segment
    float* Abuf = out + 2 * ND;   // view1 segment (scratch)
    float* Bbuf = out + 3 * ND;   // view2 segment (scratch)

    const int n4  = (int)(ND / 4);
    const int nu4 = NUM_USER * D / 4;

    k_init<<<2048, 256, 0, stream>>>((const float4*)ue, (const float4*)ie,
                                     (float4*)Abuf, (float4*)Bbuf,
                                     (float4*)acc, n4, nu4);

    float* A = Abuf;
    float* B = Bbuf;
    for (int l = 0; l < LAYERS; ++l) {   // gcn_layer == 3, constant per problem
        k_spmm<<<4096, 256, 0, stream>>>(rows, cols, vals, A, B, nnz);
        k_post<<<2048, 256, 0, stream>>>((float4*)acc, (const float4*)B,
                                         (float4*)A, n4);
        float* t = A; A = B; B = t;
    }

    k_final<<<2048, 256, 0, stream>>>(acc, W, bias, n1, n2,
                                      stdo, Abuf, Bbuf, N_TOTAL);
}

// Round 2
// 920.718 us; speedup vs baseline: 1.9561x; 1.9561x over previous
//
#include <hip/hip_runtime.h>
#include <math.h>

#define NUM_USER 150000
#define NUM_ITEM 75000
#define N_TOTAL  225000
#define D        64
#define LAYERS   3
#define SCALE    0.01f
#define SCAN_TILE 2048          // 256 threads x 8 items

// ---------------------------------------------------------------------------
// zero the histogram counters
// ---------------------------------------------------------------------------
__global__ void k_zero(int* __restrict__ p, int n) {
    for (int i = blockIdx.x * blockDim.x + threadIdx.x; i < n;
         i += gridDim.x * blockDim.x)
        p[i] = 0;
}

// ---------------------------------------------------------------------------
// histogram of destination rows
// ---------------------------------------------------------------------------
__global__ void k_hist(const int* __restrict__ rows, int* __restrict__ cnt, int nnz) {
    for (int e = blockIdx.x * blockDim.x + threadIdx.x; e < nnz;
         e += gridDim.x * blockDim.x)
        atomicAdd(&cnt[rows[e]], 1);
}

// ---------------------------------------------------------------------------
// scan stage 1: per-block (2048-wide) exclusive scan of cnt -> off, block sums
// ---------------------------------------------------------------------------
__global__ __launch_bounds__(256) void k_scan1(const int* __restrict__ cnt,
                                               int* __restrict__ off,
                                               int* __restrict__ bsum, int n) {
    __shared__ int sd[256];
    const int t = threadIdx.x;
    const int base = blockIdx.x * SCAN_TILE + t * 8;
    int v[8], s = 0;
#pragma unroll
    for (int i = 0; i < 8; ++i) {
        int idx = base + i;
        v[i] = (idx < n) ? cnt[idx] : 0;
        s += v[i];
    }
    sd[t] = s;
    __syncthreads();
#pragma unroll
    for (int o = 1; o < 256; o <<= 1) {
        int x = (t >= o) ? sd[t - o] : 0;
        __syncthreads();
        if (t >= o) sd[t] += x;
        __syncthreads();
    }
    int run = (t == 0) ? 0 : sd[t - 1];
#pragma unroll
    for (int i = 0; i < 8; ++i) {
        int idx = base + i;
        if (idx < n) off[idx] = run;
        run += v[i];
    }
    if (t == 255) bsum[blockIdx.x] = sd[255];
}

// ---------------------------------------------------------------------------
// scan stage 2: single block, exclusive scan of block sums in place (nb<=2048)
// ---------------------------------------------------------------------------
__global__ __launch_bounds__(256) void k_scan2(int* __restrict__ bsum, int nb) {
    __shared__ int sd[256];
    const int t = threadIdx.x;
    const int base = t * 8;
    int v[8], s = 0;
#pragma unroll
    for (int i = 0; i < 8; ++i) {
        int idx = base + i;
        v[i] = (idx < nb) ? bsum[idx] : 0;
        s += v[i];
    }
    sd[t] = s;
    __syncthreads();
#pragma unroll
    for (int o = 1; o < 256; o <<= 1) {
        int x = (t >= o) ? sd[t - o] : 0;
        __syncthreads();
        if (t >= o) sd[t] += x;
        __syncthreads();
    }
    int run = (t == 0) ? 0 : sd[t - 1];
#pragma unroll
    for (int i = 0; i < 8; ++i) {
        int idx = base + i;
        if (idx < nb) bsum[idx] = run;
        run += v[i];
    }
}

// ---------------------------------------------------------------------------
// scan stage 3: add block offsets, init scatter cursors, write off[N]=nnz
// ---------------------------------------------------------------------------
__global__ __launch_bounds__(256) void k_scan3(int* __restrict__ off,
                                               int* __restrict__ cur,
                                               const int* __restrict__ bsum,
                                               int n, int nnz) {
    const int blk = blockIdx.x;
    const int s = bsum[blk];
    const int base = blk * SCAN_TILE + threadIdx.x * 8;
#pragma unroll
    for (int i = 0; i < 8; ++i) {
        int idx = base + i;
        if (idx < n) {
            int o = off[idx] + s;
            off[idx] = o;
            cur[idx] = o;
        }
    }
    if (blk == 0 && threadIdx.x == 0) off[n] = nnz;
}

// ---------------------------------------------------------------------------
// scatter edges into CSR order
// ---------------------------------------------------------------------------
__global__ void k_scatter(const int* __restrict__ rows, const int* __restrict__ cols,
                          const float* __restrict__ vals, int* __restrict__ cur,
                          int* __restrict__ csr_c, float* __restrict__ csr_v, int nnz) {
    for (int e = blockIdx.x * blockDim.x + threadIdx.x; e < nnz;
         e += gridDim.x * blockDim.x) {
        int r = rows[e];
        int p = atomicAdd(&cur[r], 1);
        csr_c[p] = cols[e];
        csr_v[p] = vals[e];
    }
}

// ---------------------------------------------------------------------------
// CSR SpMM, one wave per row, lane = dim.  No atomics.
// MODE 0: first layer  (gather from ue/ie, acc  = y, write y)
// MODE 1: mid layer    (gather from xbuf,  acc += y, write y)
// MODE 2: last layer   (gather from xbuf,  acc += y, skip y write)
// ---------------------------------------------------------------------------
template <int MODE>
__global__ __launch_bounds__(256) void k_spmm_csr(
        const int* __restrict__ off, const int* __restrict__ csr_c,
        const float* __restrict__ csr_v,
        const float* __restrict__ ue, const float* __restrict__ ie,
        const float* __restrict__ xbuf,
        float* __restrict__ ybuf, float* __restrict__ accbuf, int nrows) {
    const int lane = threadIdx.x & 63;
    const int w0   = (blockIdx.x * blockDim.x + threadIdx.x) >> 6;
    const int nw   = (gridDim.x * blockDim.x) >> 6;

    for (int r0 = w0; r0 < nrows; r0 += nw) {
        const int r = __builtin_amdgcn_readfirstlane(r0);
        const int s = off[r];
        const int e = off[r + 1];
        float accv = 0.f;
        for (int base = s; base < e; base += 64) {
            const int nv = min(64, e - base);
            int   cv = 0;
            float vv = 0.f;
            if (lane < nv) {
                cv = csr_c[base + lane];
                vv = csr_v[base + lane];
            }
            int j = 0;
            for (; j + 4 <= nv; j += 4) {
                int c0 = __shfl(cv, j),     c1 = __shfl(cv, j + 1);
                int c2 = __shfl(cv, j + 2), c3 = __shfl(cv, j + 3);
                float v0 = __shfl(vv, j),     v1 = __shfl(vv, j + 1);
                float v2 = __shfl(vv, j + 2), v3 = __shfl(vv, j + 3);
                float x0, x1, x2, x3;
                if (MODE == 0) {
                    x0 = (c0 < NUM_USER) ? ue[c0 * D + lane] : ie[(c0 - NUM_USER) * D + lane];
                    x1 = (c1 < NUM_USER) ? ue[c1 * D + lane] : ie[(c1 - NUM_USER) * D + lane];
                    x2 = (c2 < NUM_USER) ? ue[c2 * D + lane] : ie[(c2 - NUM_USER) * D + lane];
                    x3 = (c3 < NUM_USER) ? ue[c3 * D + lane] : ie[(c3 - NUM_USER) * D + lane];
                } else {
                    x0 = xbuf[c0 * D + lane]; x1 = xbuf[c1 * D + lane];
                    x2 = xbuf[c2 * D + lane]; x3 = xbuf[c3 * D + lane];
                }
                accv = fmaf(v0, x0, accv);
                accv = fmaf(v1, x1, accv);
                accv = fmaf(v2, x2, accv);
                accv = fmaf(v3, x3, accv);
            }
            for (; j < nv; ++j) {
                int   c = __shfl(cv, j);
                float v = __shfl(vv, j);
                float x;
                if (MODE == 0)
                    x = (c < NUM_USER) ? ue[c * D + lane] : ie[(c - NUM_USER) * D + lane];
                else
                    x = xbuf[c * D + lane];
                accv = fmaf(v, x, accv);
            }
        }
        const int o = r * D + lane;
        if (MODE == 0) accbuf[o] = accv;
        else           accbuf[o] += accv;
        if (MODE != 2) ybuf[o] = accv;
    }
}

// ---------------------------------------------------------------------------
// final: mean = acc/3; logstd = mean @ W + b; std = exp; views
// ---------------------------------------------------------------------------
__global__ __launch_bounds__(256) void k_final(
        float* __restrict__ mean_io,
        const float* __restrict__ W, const float* __restrict__ bias,
        const float* __restrict__ n1, const float* __restrict__ n2,
        float* __restrict__ std_out, float* __restrict__ v1,
        float* __restrict__ v2, int nrows) {
    __shared__ float Wl[64 * 64];
    __shared__ float rowbuf[4][64];
    for (int i = threadIdx.x; i < 64 * 64; i += blockDim.x) Wl[i] = W[i];
    __syncthreads();

    const int   lane = threadIdx.x & 63;
    const int   wv   = threadIdx.x >> 6;
    const float bj   = bias[lane];
    const int   w0   = blockIdx.x * 4 + wv;
    const int   nw   = gridDim.x * 4;

    for (int r = w0; r < nrows; r += nw) {
        const size_t base = (size_t)r * D;
        float m = mean_io[base + lane] * (1.f / 3.f);
        rowbuf[wv][lane] = m;
        float s = bj;
#pragma unroll
        for (int k = 0; k < 64; ++k)
            s = fmaf(rowbuf[wv][k], Wl[k * 64 + lane], s);
        float sd = __expf(s);
        mean_io[base + lane] = m;
        std_out[base + lane] = sd;
        v1[base + lane] = fmaf(sd * SCALE, n1[base + lane], m);
        v2[base + lane] = fmaf(sd * SCALE, n2[base + lane], m);
    }
}

// ---------------------------------------------------------------------------
extern "C" void kernel_launch(void* const* d_in, const int* in_sizes, int n_in,
                              void* d_out, int out_size, void* d_ws, size_t ws_size,
                              hipStream_t stream) {
    const float* ue   = (const float*)d_in[0];
    const float* ie   = (const float*)d_in[1];
    const float* W    = (const float*)d_in[2];
    const float* bias = (const float*)d_in[3];
    const int*   rows = (const int*)d_in[4];
    const int*   cols = (const int*)d_in[5];
    const float* vals = (const float*)d_in[6];
    const float* n1   = (const float*)d_in[7];
    const float* n2   = (const float*)d_in[8];
    const int    nnz  = in_sizes[4];

    float* out = (float*)d_out;
    const size_t ND = (size_t)N_TOTAL * D;

    // d_out layout: [mean | std | view1 | view2]
    // seg1 (std) doubles as CSR scratch until k_final; seg2/3 are ego ping-pong.
    float* acc  = out;            // mean segment: layer accumulator -> mean
    float* stdo = out + ND;       // std segment: CSR scratch now, std at end
    float* y1   = out + 2 * ND;   // view1 segment: ego after layer 1
    float* y2   = out + 3 * ND;   // view2 segment: ego after layer 2

    // carve CSR arrays out of the std segment (needs ~18.7 MB of 57.6 MB)
    int*   ws    = (int*)stdo;
    int*   cnt   = ws;                         // N
    int*   off   = ws + 225024;                // N+1
    int*   cur   = ws + 450048;                // N
    int*   bsum  = ws + 675072;                // <=2048
    int*   csr_c = ws + 677120;                // nnz
    float* csr_v = (float*)(ws + 2677120);     // nnz

    const int nb = (N_TOTAL + SCAN_TILE - 1) / SCAN_TILE;   // 110

    // --- build CSR (every call; inputs/ws are re-poisoned by harness) ---
    k_zero<<<256, 256, 0, stream>>>(cnt, N_TOTAL);
    k_hist<<<2048, 256, 0, stream>>>(rows, cnt, nnz);
    k_scan1<<<nb, 256, 0, stream>>>(cnt, off, bsum, N_TOTAL);
    k_scan2<<<1, 256, 0, stream>>>(bsum, nb);
    k_scan3<<<nb, 256, 0, stream>>>(off, cur, bsum, N_TOTAL, nnz);
    k_scatter<<<2048, 256, 0, stream>>>(rows, cols, vals, cur, csr_c, csr_v, nnz);

    // --- 3 GCN layers, no atomics, acc fused ---
    k_spmm_csr<0><<<2048, 256, 0, stream>>>(off, csr_c, csr_v, ue, ie, nullptr,
                                            y1, acc, N_TOTAL);
    k_spmm_csr<1><<<2048, 256, 0, stream>>>(off, csr_c, csr_v, nullptr, nullptr, y1,
                                            y2, acc, N_TOTAL);
    k_spmm_csr<2><<<2048, 256, 0, stream>>>(off, csr_c, csr_v, nullptr, nullptr, y2,
                                            nullptr, acc, N_TOTAL);

    // --- epilogue (overwrites all four output segments) ---
    k_final<<<2048, 256, 0, stream>>>(acc, W, bias, n1, n2,
                                      stdo, y1, y2, N_TOTAL);
}